// Round 1
// baseline (583.536 us; speedup 1.0000x reference)
//
#include <hip/hip_runtime.h>

// Problem constants (fixed by the reference's setup_inputs)
#define NN   100000      // nodes
#define EE   1600000     // num_edge
#define EROW 4800000     // edge_index row length (3*NUM_EDGE)

__device__ __forceinline__ float4 ld4(const float* p){ return *(const float4*)p; }

// ---------------------------------------------------------------------------
// Tiled fp32 SGEMM: out[M x Ncols] = act( A[M x K] @ B[Ncols x K]^T + bias )
// BM=BN=128, BK=16, 256 threads, 8x8 per thread (split 4+4 halves).
// MODE 0: A is "virtual x" gathered from trace_all (two L-halves); relu output.
// MODE 1: plain A, plain output.
// MODE 2: B is repacked view of W_fc1 (rows 0-63 = left half, 64-127 = right
//         half); bias = b_fc1 added to first 64 output cols only.
// ---------------------------------------------------------------------------
template<int MODE>
__global__ __launch_bounds__(256, 2)
void gemm_k(const float* __restrict__ A, const float* __restrict__ B,
            const float* __restrict__ bias, float* __restrict__ out,
            int M, int Ncols, int K)
{
    __shared__ float As[16][132];   // [k][m], pad 132 -> stride 4 banks/row
    __shared__ float Bs[16][132];   // [k][n]

    const int t  = threadIdx.x;
    const int tx = t & 15;          // n-direction
    const int ty = t >> 4;          // m-direction
    const int mBase = blockIdx.x * 128;
    const int nBase = blockIdx.y * 128;

    float acc[8][8];
#pragma unroll
    for (int i = 0; i < 8; ++i)
#pragma unroll
        for (int j = 0; j < 8; ++j) acc[i][j] = 0.f;

    const int rA = t >> 1;          // 0..127: tile row for loads
    const int hk = (t & 1) * 8;     // which 8-float half of the 16-wide k chunk
    int mrow = mBase + rA; if (mrow >= M) mrow = M - 1;   // clamp tail rows
    const int nrow = nBase + rA;    // Ncols is a multiple of 128 -> in range

    const int kIters = K / 16;
    for (int kt = 0; kt < kIters; ++kt) {
        const int k0 = kt * 16 + hk;

        float4 a0, a1;
        if (MODE == 0) {
            // x[n][k] = trace_all[k>>7][n][k&127]
            const float* src = A + (size_t)(k0 >> 7) * (NN * 128)
                                 + (size_t)mrow * 128 + (k0 & 127);
            a0 = ld4(src); a1 = ld4(src + 4);
        } else {
            const float* src = A + (size_t)mrow * K + k0;
            a0 = ld4(src); a1 = ld4(src + 4);
        }

        float4 b0, b1;
        if (MODE == 2) {
            // B[j][k] = W_fc1[j&63][(j>>6)*128 + k], K=128
            const float* src = B + (size_t)(nrow & 63) * 256 + (nrow >> 6) * 128 + k0;
            b0 = ld4(src); b1 = ld4(src + 4);
        } else {
            const float* src = B + (size_t)nrow * K + k0;
            b0 = ld4(src); b1 = ld4(src + 4);
        }

        __syncthreads();   // previous iteration's LDS readers done
        As[hk+0][rA] = a0.x; As[hk+1][rA] = a0.y; As[hk+2][rA] = a0.z; As[hk+3][rA] = a0.w;
        As[hk+4][rA] = a1.x; As[hk+5][rA] = a1.y; As[hk+6][rA] = a1.z; As[hk+7][rA] = a1.w;
        Bs[hk+0][rA] = b0.x; Bs[hk+1][rA] = b0.y; Bs[hk+2][rA] = b0.z; Bs[hk+3][rA] = b0.w;
        Bs[hk+4][rA] = b1.x; Bs[hk+5][rA] = b1.y; Bs[hk+6][rA] = b1.z; Bs[hk+7][rA] = b1.w;
        __syncthreads();

#pragma unroll
        for (int k = 0; k < 16; ++k) {
            float4 av0 = ld4(&As[k][ty * 4]);
            float4 av1 = ld4(&As[k][64 + ty * 4]);
            float4 bv0 = ld4(&Bs[k][tx * 4]);
            float4 bv1 = ld4(&Bs[k][64 + tx * 4]);
            float am[8] = {av0.x, av0.y, av0.z, av0.w, av1.x, av1.y, av1.z, av1.w};
            float bn[8] = {bv0.x, bv0.y, bv0.z, bv0.w, bv1.x, bv1.y, bv1.z, bv1.w};
#pragma unroll
            for (int i = 0; i < 8; ++i)
#pragma unroll
                for (int j = 0; j < 8; ++j)
                    acc[i][j] = fmaf(am[i], bn[j], acc[i][j]);
        }
    }

    // Epilogue
    float4 bb = make_float4(0.f, 0.f, 0.f, 0.f);
    if (MODE == 2) bb = ld4(&bias[tx * 4]);   // first-half cols get b_fc1

#pragma unroll
    for (int i = 0; i < 8; ++i) {
        const int mloc = (i < 4) ? (ty * 4 + i) : (64 + ty * 4 + (i - 4));
        const int m = mBase + mloc;
        if (m < M) {
            float* orow = out + (size_t)m * Ncols + nBase;
            float v0x = acc[i][0], v0y = acc[i][1], v0z = acc[i][2], v0w = acc[i][3];
            float v1x = acc[i][4], v1y = acc[i][5], v1z = acc[i][6], v1w = acc[i][7];
            if (MODE == 2) { v0x += bb.x; v0y += bb.y; v0z += bb.z; v0w += bb.w; }
            if (MODE == 0) {
                v0x = fmaxf(v0x, 0.f); v0y = fmaxf(v0y, 0.f);
                v0z = fmaxf(v0z, 0.f); v0w = fmaxf(v0w, 0.f);
                v1x = fmaxf(v1x, 0.f); v1y = fmaxf(v1y, 0.f);
                v1z = fmaxf(v1z, 0.f); v1w = fmaxf(v1w, 0.f);
            }
            *(float4*)&orow[tx * 4]      = make_float4(v0x, v0y, v0z, v0w);
            *(float4*)&orow[64 + tx * 4] = make_float4(v1x, v1y, v1z, v1w);
        }
    }
}

// ---------------------------------------------------------------------------
// L2-normalize mvc rows in place: one wave per node (2 elems/lane).
// ---------------------------------------------------------------------------
__global__ __launch_bounds__(256, 4)
void norm_k(float* __restrict__ mvc)
{
    const int t = threadIdx.x;
    const int node = blockIdx.x * 4 + (t >> 6);
    const int lane = t & 63;
    float* row = mvc + (size_t)node * 128;
    float a = row[lane];
    float b = row[64 + lane];
    float ss = a * a + b * b;
#pragma unroll
    for (int off = 32; off; off >>= 1) ss += __shfl_xor(ss, off, 64);
    float nrm = fmaxf(sqrtf(ss), 1e-12f);
    row[lane]      = a / nrm;
    row[64 + lane] = b / nrm;
}

// ---------------------------------------------------------------------------
// Edge kernel: 64 edges/block, 16 lanes per edge.
// v = relu(p[src][0:64] + p[dst][64:128]); s = W_fc2 @ v + b_fc2;
// active = (s0+g0 >= s1+g1); train_mask = [active, 1-active, 1-active].
// ---------------------------------------------------------------------------
__global__ __launch_bounds__(256, 4)
void edge_k(const float* __restrict__ p, const int* __restrict__ ei,
            const float* __restrict__ gum, const float* __restrict__ W2,
            const float* __restrict__ b2, float* __restrict__ out)
{
    __shared__ int   sidx[64];
    __shared__ int   didx[64];
    __shared__ float gl[128];
    __shared__ float act[64];

    const int t  = threadIdx.x;
    const int e0 = blockIdx.x * 64;

    if (t < 64)                sidx[t]      = ei[e0 + t];
    else if (t < 128)          didx[t - 64] = ei[EROW + e0 + (t - 64)];
    if (t < 128)               gl[t]        = gum[(size_t)e0 * 2 + t];
    __syncthreads();

    const int j   = t & 15;    // lane within edge group
    const int grp = t >> 4;    // 16 groups
    const float4 w0 = ld4(&W2[j * 4]);
    const float4 w1 = ld4(&W2[64 + j * 4]);
    const float b20 = b2[0], b21 = b2[1];

#pragma unroll
    for (int it = 0; it < 4; ++it) {
        const int el = grp * 4 + it;
        const int s  = sidx[el];
        const int d  = didx[el];
        const float4 pa = ld4(&p[(size_t)s * 128 + j * 4]);
        const float4 pb = ld4(&p[(size_t)d * 128 + 64 + j * 4]);
        const float r0 = fmaxf(pa.x + pb.x, 0.f);
        const float r1 = fmaxf(pa.y + pb.y, 0.f);
        const float r2 = fmaxf(pa.z + pb.z, 0.f);
        const float r3 = fmaxf(pa.w + pb.w, 0.f);
        float s0 = r0 * w0.x + r1 * w0.y + r2 * w0.z + r3 * w0.w;
        float s1 = r0 * w1.x + r1 * w1.y + r2 * w1.z + r3 * w1.w;
#pragma unroll
        for (int off = 1; off < 16; off <<= 1) {
            s0 += __shfl_xor(s0, off, 16);
            s1 += __shfl_xor(s1, off, 16);
        }
        if (j == 0) {
            const float sc0 = s0 + b20 + gl[el * 2];
            const float sc1 = s1 + b21 + gl[el * 2 + 1];
            act[el] = (sc0 >= sc1) ? 1.f : 0.f;   // argmax ties -> index 0
        }
    }
    __syncthreads();

    if (t < 64) {
        const float a = act[t];
        const size_t e = (size_t)e0 + t;
        out[e]           = a;
        out[EE + e]      = 1.f - a;
        out[2 * (size_t)EE + e] = 1.f - a;
    }
}

// ---------------------------------------------------------------------------
extern "C" void kernel_launch(void* const* d_in, const int* in_sizes, int n_in,
                              void* d_out, int out_size, void* d_ws, size_t ws_size,
                              hipStream_t stream)
{
    const float* trace  = (const float*)d_in[0];   // (2,100000,128)
    const float* W_lin  = (const float*)d_in[1];   // (256,256)
    const float* W_lin2 = (const float*)d_in[2];   // (128,256)
    const float* W_fc1  = (const float*)d_in[3];   // (64,256)
    const float* b_fc1  = (const float*)d_in[4];   // (64,)
    const float* W_fc2  = (const float*)d_in[5];   // (2,64)
    const float* b_fc2  = (const float*)d_in[6];   // (2,)
    const float* gum    = (const float*)d_in[7];   // (1600000,2)
    const int*   ei     = (const int*)  d_in[8];   // (2,4800000)
    float*       out    = (float*)d_out;           // (4800000,)

    // Workspace layout: h [100k x 256] at 0 (102.4 MB); mvc [100k x 128] after
    // it (51.2 MB); p [100k x 128] reuses h's region (h dead after GEMM2).
    float* h   = (float*)d_ws;
    float* mvc = (float*)((char*)d_ws + (size_t)NN * 256 * 4);
    float* p   = (float*)d_ws;

    const int mBlocks = (NN + 127) / 128;   // 782

    // h = relu(x @ W_lin^T)
    gemm_k<0><<<dim3(mBlocks, 2), 256, 0, stream>>>(trace, W_lin, nullptr, h, NN, 256, 256);
    // mvc = h @ W_lin2^T
    gemm_k<1><<<dim3(mBlocks, 1), 256, 0, stream>>>(h, W_lin2, nullptr, mvc, NN, 128, 256);
    // normalize rows
    norm_k<<<NN / 4, 256, 0, stream>>>(mvc);
    // p[n] = [W_fc1_left @ mvcn + b_fc1 | W_fc1_right @ mvcn]
    gemm_k<2><<<dim3(mBlocks, 1), 256, 0, stream>>>(mvc, W_fc1, b_fc1, p, NN, 128, 128);
    // per-edge score + hard mask
    edge_k<<<EE / 64, 256, 0, stream>>>(p, ei, gum, W_fc2, b_fc2, out);
}